// Round 3
// baseline (1487.560 us; speedup 1.0000x reference)
//
#include <hip/hip_runtime.h>
#include <hip/hip_bf16.h>

#define DEVI __device__ __forceinline__

typedef __attribute__((ext_vector_type(8))) short short8;
typedef __attribute__((ext_vector_type(4))) float float4v;

DEVI float bf2f(__hip_bfloat16 v) { return __bfloat162float(v); }
DEVI float ldbs(const ushort* p, size_t i) { return bf2f(((const __hip_bfloat16*)p)[i]); }
DEVI ushort f2bs(float v) {
    __hip_bfloat16 h = __float2bfloat16(v);
    return *(ushort*)&h;
}
DEVI float bfs2f(short s) {
    ushort u = (ushort)s;
    return bf2f(*(__hip_bfloat16*)&u);
}

// flag-dependent element load/store: isf32 selects float32 vs bf16 view
DEVI float ldin(const void* p, size_t i, int isf32) {
    return isf32 ? ((const float*)p)[i] : bf2f(((const __hip_bfloat16*)p)[i]);
}
DEVI void stio(void* p, size_t i, float v, int isf32) {
    if (isf32) ((float*)p)[i] = v;
    else ((ushort*)p)[i] = f2bs(v);
}

// ACT: 0 none, 1 leaky(0.1), 2 leaky(0.01), 3 prelu(alpha)
template <int ACT>
DEVI float act_fn(float v, float alpha) {
    if (ACT == 1) return v >= 0.f ? v : 0.1f * v;
    if (ACT == 2) return v >= 0.f ? v : 0.01f * v;
    if (ACT == 3) return v >= 0.f ? v : alpha * v;
    return v;
}

DEVI float waveRed(float v) {
#pragma unroll
    for (int o = 32; o > 0; o >>= 1) v += __shfl_down(v, o);
    return v;
}

DEVI float blockRed(float v) {
    __shared__ float sm[16];
    int lane = threadIdx.x & 63, w = threadIdx.x >> 6;
    v = waveRed(v);
    if (lane == 0) sm[w] = v;
    __syncthreads();
    if (w == 0) {
        int nw = (blockDim.x + 63) >> 6;
        v = (lane < nw) ? sm[lane] : 0.f;
        v = waveRed(v);
    }
    return v;  // valid on thread 0
}

// ---------------- dtype probe ----------------
__global__ void probe_k(const void* __restrict__ x, int* __restrict__ flag) {
    __shared__ int sfails;
    int t = threadIdx.x;
    if (t == 0) sfails = 0;
    __syncthreads();
    const __hip_bfloat16* xb = (const __hip_bfloat16*)x;
    int my = 0;
    for (int i = t; i < 4096; i += 256) {
        float v = bf2f(xb[i]);
        float a = fabsf(v);
        if (!(a <= 64.f) || (v != 0.f && a < 1e-6f)) my++;
    }
    atomicAdd(&sfails, my);
    __syncthreads();
    if (t == 0) flag[0] = (sfails > 409) ? 1 : 0;  // >10% fail => inputs are float32
}

// ---------------- fused weight transpose+convert (5 weights in one launch) ----
struct Cvt5 {
    const void* src[5];
    ushort* dst[5];
    int K[5];
    int N[5];
};
__global__ void cvt_all_k(Cvt5 d, const int* __restrict__ flagp) {
    int f32 = flagp[0];
    int seg = blockIdx.y;
    int idx = blockIdx.x * blockDim.x + threadIdx.x;
    int K = d.K[seg], Nc = d.N[seg];
    int total = K * Nc;
    if (idx < total) {
        int k = idx / Nc, n = idx % Nc;
        d.dst[seg][(size_t)n * K + k] = f2bs(ldin(d.src[seg], idx, f32));
    }
}

// ---------------- MFMA bf16 GEMM ----------------
// C[M][Nc] = act(A[M][K] @ Bt[Nc][K]^T + bias_eff)
// 128x128 tile, 256 threads (4 waves 2x2), 16x16x32 MFMA, BK=32, pitch 40 shorts.
// Grid is (NT, MT): N-tiles fastest for A-panel L2 reuse.
// Issue/commit staging split with 1-tile register prefetch (R2 win: vmcnt wait
// lands a full compute phase after issue).
// AMODE: 0 = A is flag-typed model input, 1 = A is bf16 workspace
// OMODE: 0 = out bf16 ws (stride LDo); 1 = d_out (flag-typed,+1) AND outp2 bf16 ws
// BMODE: 0 = bias[n]; 1 = rsc[m]*bias[n]  (row-scaled bias for spmm-reordered path)
#define TP 40
template <int AMODE, int ACT, int OMODE, int BMODE>
__global__ __launch_bounds__(256) void mgemm_k(
    const void* __restrict__ A, const ushort* __restrict__ Bt,
    const void* __restrict__ bias, const float* __restrict__ rsc,
    const void* __restrict__ alpha_p, void* __restrict__ outp, ushort* __restrict__ outp2,
    const int* __restrict__ flagp, int M, int K, int Nc, int LDo) {
    __shared__ short As[128 * TP];
    __shared__ short Bs[128 * TP];
    const int f32 = flagp[0];
    const int tid = threadIdx.x;
    const int lane = tid & 63;
    const int l15 = lane & 15;
    const int quad = lane >> 4;
    const int wid = tid >> 6;
    const int mW = (wid >> 1) * 64;
    const int nW = (wid & 1) * 64;
    const int mBase = blockIdx.y * 128;
    const int nBase = blockIdx.x * 128;

    float4v acc[4][4];
#pragma unroll
    for (int i = 0; i < 4; i++)
#pragma unroll
        for (int j = 0; j < 4; j++) acc[i][j] = (float4v){0.f, 0.f, 0.f, 0.f};

    // staging registers (raw bits; converted at commit)
    short8 sa[2], sb[2];
    float4v fa[2][2];

    auto issue_tile = [&](int k0) {
#pragma unroll
        for (int i = 0; i < 2; i++) {
            int chunk = i * 256 + tid;
            int row = chunk >> 2;
            int c = chunk & 3;
            int gr = mBase + row;
            int gn = nBase + row;
            size_t geA = (size_t)gr * K + k0 + c * 8;
            if (AMODE == 0 && f32) {
                if (gr < M) {
                    const float* af = (const float*)A + geA;
                    fa[i][0] = *(const float4v*)af;
                    fa[i][1] = *(const float4v*)(af + 4);
                } else {
                    fa[i][0] = (float4v){0.f, 0.f, 0.f, 0.f};
                    fa[i][1] = (float4v){0.f, 0.f, 0.f, 0.f};
                }
            } else {
                sa[i] = (gr < M) ? *(const short8*)((const ushort*)A + geA)
                                 : (short8){0, 0, 0, 0, 0, 0, 0, 0};
            }
            sb[i] = (gn < Nc) ? *(const short8*)(Bt + (size_t)gn * K + k0 + c * 8)
                              : (short8){0, 0, 0, 0, 0, 0, 0, 0};
        }
    };

    auto commit_tile = [&]() {
#pragma unroll
        for (int i = 0; i < 2; i++) {
            int chunk = i * 256 + tid;
            int row = chunk >> 2;
            int c = chunk & 3;
            short8 va;
            if (AMODE == 0 && f32) {
#pragma unroll
                for (int j = 0; j < 4; j++) va[j] = (short)f2bs(fa[i][0][j]);
#pragma unroll
                for (int j = 0; j < 4; j++) va[4 + j] = (short)f2bs(fa[i][1][j]);
            } else {
                va = sa[i];
            }
            *(short8*)&As[row * TP + c * 8] = va;
            *(short8*)&Bs[row * TP + c * 8] = sb[i];
        }
    };

    const int nk = K >> 5;
    issue_tile(0);
    for (int t = 0; t < nk; ++t) {
        __syncthreads();  // previous tile's readers done
        commit_tile();    // vmcnt wait lands here (issue was a full phase ago)
        if (t + 1 < nk) issue_tile((t + 1) << 5);  // in flight across barrier+compute
        __syncthreads();  // LDS tile ready

        short8 af[4], bf[4];
#pragma unroll
        for (int i = 0; i < 4; i++)
            af[i] = *(const short8*)&As[(mW + i * 16 + l15) * TP + quad * 8];
#pragma unroll
        for (int j = 0; j < 4; j++)
            bf[j] = *(const short8*)&Bs[(nW + j * 16 + l15) * TP + quad * 8];
#pragma unroll
        for (int i = 0; i < 4; i++)
#pragma unroll
            for (int j = 0; j < 4; j++)
                acc[i][j] =
                    __builtin_amdgcn_mfma_f32_16x16x32_bf16(af[i], bf[j], acc[i][j], 0, 0, 0);
    }

    const float alpha = (ACT == 3) ? ldin(alpha_p, 0, f32) : 0.f;
#pragma unroll
    for (int i = 0; i < 4; i++) {
#pragma unroll
        for (int j = 0; j < 4; j++) {
            int gcn = nBase + nW + j * 16 + l15;
            if (gcn >= Nc) continue;
            float bv = ldin(bias, gcn, f32);
#pragma unroll
            for (int r = 0; r < 4; r++) {
                int grm = mBase + mW + i * 16 + quad * 4 + r;
                if (grm >= M) continue;
                float be = (BMODE == 1) ? rsc[grm] * bv : bv;
                float v = act_fn<ACT>(acc[i][j][r] + be, alpha);
                if (OMODE == 1) {
                    stio(outp, 1 + (size_t)grm * Nc + gcn, v, f32);
                    outp2[(size_t)grm * LDo + gcn] = f2bs(v);
                } else {
                    ((ushort*)outp)[(size_t)grm * LDo + gcn] = f2bs(v);
                }
            }
        }
    }
}

// ---------------- CSR build (generic: used for adjacency and agg segments) ---
__global__ void count_k(const int* __restrict__ rows, int* __restrict__ counts, int nnz) {
    int i = blockIdx.x * blockDim.x + threadIdx.x;
    if (i < nnz) atomicAdd(&counts[rows[i]], 1);
}

__global__ __launch_bounds__(1024) void scan_local_k(const int* __restrict__ counts,
                                                     int* __restrict__ offs,
                                                     int* __restrict__ bsums, int n) {
    __shared__ int sm[1024];
    int t = threadIdx.x;
    int g = blockIdx.x * 1024 + t;
    int v = (g < n) ? counts[g] : 0;
    sm[t] = v;
    __syncthreads();
    for (int d = 1; d < 1024; d <<= 1) {
        int add = (t >= d) ? sm[t - d] : 0;
        __syncthreads();
        sm[t] += add;
        __syncthreads();
    }
    if (g < n) offs[g] = sm[t] - v;  // exclusive
    if (t == 1023) bsums[blockIdx.x] = sm[t];
}

__global__ void scan_bsums_k(int* bsums, int nb) {
    if (threadIdx.x == 0 && blockIdx.x == 0) {
        int acc = 0;
        for (int i = 0; i < nb; i++) {
            int v = bsums[i];
            bsums[i] = acc;
            acc += v;
        }
    }
}

__global__ void scan_add_k(int* __restrict__ offs, const int* __restrict__ bsums, int n, int nnz) {
    int g = blockIdx.x * blockDim.x + threadIdx.x;
    if (g < n) offs[g] += bsums[g >> 10];
    if (g == 0) offs[n] = nnz;
}

// adjacency fill: pre-applies perm for colsp; accumulates row-sums r = S*1
__global__ void fill_k(const int* __restrict__ rows, const int* __restrict__ cols,
                       const void* __restrict__ vals, const int* __restrict__ perm,
                       const int* __restrict__ offs, int* __restrict__ cursor,
                       int* __restrict__ cols_s, int* __restrict__ colsp_s,
                       float* __restrict__ vals_s, float* __restrict__ rsum,
                       const int* __restrict__ flagp, int nnz) {
    int e = blockIdx.x * blockDim.x + threadIdx.x;
    if (e < nnz) {
        int r = rows[e];
        int pos = offs[r] + atomicAdd(&cursor[r], 1);
        int c = cols[e];
        float v = ldin(vals, e, flagp[0]);
        cols_s[pos] = c;
        colsp_s[pos] = perm[c];
        vals_s[pos] = v;
        atomicAdd(&rsum[r], v);
    }
}

// agg segment fill (source index = element position)
__global__ void fill_s_k(const int* __restrict__ rows, const void* __restrict__ vals,
                         const int* __restrict__ offs, int* __restrict__ cursor,
                         int* __restrict__ idx_s, float* __restrict__ val_s,
                         const int* __restrict__ flagp, int n) {
    int e = blockIdx.x * blockDim.x + threadIdx.x;
    if (e < n) {
        int r = rows[e];
        int pos = offs[r] + atomicAdd(&cursor[r], 1);
        idx_s[pos] = e;
        val_s[pos] = ldin(vals, e, flagp[0]);
    }
}

// ---------------- feature-sliced SpMM (XCD-pinned L2-resident gathers) -------
// F=256 split into 8 slices of 32 elems (64 B). Block b handles slice b&7 and
// row-group b>>3; round-robin block->XCD dispatch pins slice s to XCD s, so
// each XCD's gather working set is F_total/8 * N = 3.2 MB < 4 MB L2.
// Wave lane map: e = lane>>2 (16 parallel edges), ch = lane&3 (4 chunks of 8).
// Butterfly shfl_xor over masks {4,8,16,32} reduces across the 16 edge groups.
// DUAL: second gather stream via colsp (perm) into out2.
template <int ACT, bool DUAL>
__global__ __launch_bounds__(256) void spmms_k(
    const int* __restrict__ offs, const int* __restrict__ cols_s,
    const int* __restrict__ colsp_s, const float* __restrict__ vals_s,
    const void* __restrict__ alpha_p, const int* __restrict__ flagp,
    const ushort* __restrict__ Min, ushort* __restrict__ out1, ushort* __restrict__ out2,
    int Nrow, int LD) {
    int bid = blockIdx.x;
    int slice = bid & 7;
    int row = (bid >> 3) * 4 + (threadIdx.x >> 6);
    if (row >= Nrow) return;
    int lane = threadIdx.x & 63;
    int e = lane >> 2, ch = lane & 3;
    int sbase = slice * 32 + ch * 8;  // element offset within a row
    float alpha = (ACT == 3) ? ldin(alpha_p, 0, flagp[0]) : 0.f;
    int s = offs[row], en = offs[row + 1];
    float a[8] = {}, b[8] = {};
    for (int i = s + e; i < en; i += 16) {
        int c = cols_s[i];
        float v = vals_s[i];
        short8 h = *(const short8*)(Min + (size_t)c * LD + sbase);
#pragma unroll
        for (int j = 0; j < 8; j++) a[j] += v * bfs2f(h[j]);
        if (DUAL) {
            int cp = colsp_s[i];
            short8 g = *(const short8*)(Min + (size_t)cp * LD + sbase);
#pragma unroll
            for (int j = 0; j < 8; j++) b[j] += v * bfs2f(g[j]);
        }
    }
#pragma unroll
    for (int m = 4; m < 64; m <<= 1) {
#pragma unroll
        for (int j = 0; j < 8; j++) {
            a[j] += __shfl_xor(a[j], m);
            if (DUAL) b[j] += __shfl_xor(b[j], m);
        }
    }
    if (e == 0) {
        short8 o;
        size_t obase = (size_t)row * LD + sbase;
#pragma unroll
        for (int j = 0; j < 8; j++) o[j] = (short)f2bs(act_fn<ACT>(a[j], alpha));
        *(short8*)(out1 + obase) = o;
        if (DUAL) {
#pragma unroll
            for (int j = 0; j < 8; j++) o[j] = (short)f2bs(act_fn<ACT>(b[j], alpha));
            *(short8*)(out2 + obase) = o;
        }
    }
}

// ---------------- fused agg segment-sum + MSE (gather, no atomics on agg) ----
__global__ __launch_bounds__(256) void aggmse_k(
    const int* __restrict__ soffs, const int* __restrict__ sidx, const float* __restrict__ sval,
    const ushort* __restrict__ xp, const void* __restrict__ y, const int* __restrict__ flagp,
    float* __restrict__ lacc, int S, int F, int LDxp) {
    int srow = blockIdx.x * 4 + (threadIdx.x >> 6);
    int lane = threadIdx.x & 63;
    int half = lane >> 5, l5 = lane & 31;
    int FC = F >> 3;
    bool has1 = (l5 + 32) < FC;
    float a0[8] = {}, a1[8] = {};
    if (srow < S) {
        int s = soffs[srow], e = soffs[srow + 1];
        constexpr int DEPTH = 4;
        int i = s + half;
        for (; i + 2 * (DEPTH - 1) < e; i += 2 * DEPTH) {
            int n[DEPTH];
            float v[DEPTH];
#pragma unroll
            for (int u = 0; u < DEPTH; u++) {
                n[u] = sidx[i + 2 * u];
                v[u] = sval[i + 2 * u];
            }
            short8 h0v[DEPTH], h1v[DEPTH];
#pragma unroll
            for (int u = 0; u < DEPTH; u++) {
                const ushort* src = xp + (size_t)n[u] * LDxp;
                h0v[u] = *(const short8*)(src + l5 * 8);
                if (has1) h1v[u] = *(const short8*)(src + (l5 + 32) * 8);
            }
#pragma unroll
            for (int u = 0; u < DEPTH; u++) {
#pragma unroll
                for (int j = 0; j < 8; j++) a0[j] += v[u] * bfs2f(h0v[u][j]);
                if (has1) {
#pragma unroll
                    for (int j = 0; j < 8; j++) a1[j] += v[u] * bfs2f(h1v[u][j]);
                }
            }
        }
        for (; i < e; i += 2) {
            float v = sval[i];
            int n = sidx[i];
            const ushort* src = xp + (size_t)n * LDxp;
            short8 h = *(const short8*)(src + l5 * 8);
#pragma unroll
            for (int j = 0; j < 8; j++) a0[j] += v * bfs2f(h[j]);
            if (has1) {
                short8 h2 = *(const short8*)(src + (l5 + 32) * 8);
#pragma unroll
                for (int j = 0; j < 8; j++) a1[j] += v * bfs2f(h2[j]);
            }
        }
    }
#pragma unroll
    for (int j = 0; j < 8; j++) {
        a0[j] += __shfl_xor(a0[j], 32);
        if (has1) a1[j] += __shfl_xor(a1[j], 32);
    }
    float ss = 0.f;
    if (srow < S && half == 0) {
        int f32 = flagp[0];
        size_t base = (size_t)srow * F;
#pragma unroll
        for (int j = 0; j < 8; j++) {
            float d = a0[j] - ldin(y, base + l5 * 8 + j, f32);
            ss += d * d;
        }
        if (has1) {
#pragma unroll
            for (int j = 0; j < 8; j++) {
                float d = a1[j] - ldin(y, base + (l5 + 32) * 8 + j, f32);
                ss += d * d;
            }
        }
    }
    ss = blockRed(ss);
    if (threadIdx.x == 0) atomicAdd(&lacc[0], ss);
}

// ---------------- BatchNorm (bf16 h, in-place apply) ----------------
__global__ __launch_bounds__(256) void bn_stats_k(const ushort* __restrict__ h,
                                                  float* __restrict__ sum,
                                                  float* __restrict__ sumsq, int nrows, int rpb) {
    int c = threadIdx.x;
    int rs = blockIdx.x * rpb;
    int re = min(rs + rpb, nrows);
    float s = 0.f, s2 = 0.f;
    int H = blockDim.x;
    for (int r = rs; r < re; r++) {
        float v = ldbs(h, (size_t)r * H + c);
        s += v;
        s2 += v * v;
    }
    atomicAdd(&sum[c], s);
    atomicAdd(&sumsq[c], s2);
}

__global__ void bn_final_k(const float* __restrict__ sum, const float* __restrict__ sumsq,
                           const void* __restrict__ gamma, const void* __restrict__ beta,
                           float* __restrict__ scale, float* __restrict__ shift,
                           const int* __restrict__ flagp, int nrows) {
    int c = threadIdx.x;
    int f32 = flagp[0];
    float mu = sum[c] / nrows;
    float var = sumsq[c] / nrows - mu * mu;
    float sc = ldin(gamma, c, f32) * rsqrtf(var + 1e-5f);
    scale[c] = sc;
    shift[c] = ldin(beta, c, f32) - mu * sc;
}

// vectorized in-place BN apply: 8 bf16 per thread
__global__ __launch_bounds__(256) void bn_apply_k(ushort* __restrict__ h,
                                                  const float* __restrict__ scale,
                                                  const float* __restrict__ shift, int total8,
                                                  int H) {
    int idx = blockIdx.x * 256 + threadIdx.x;
    if (idx >= total8) return;
    size_t base = (size_t)idx * 8;
    int c = (int)(base % H);
    short8 v = *(short8*)(h + base);
    short8 o;
#pragma unroll
    for (int j = 0; j < 8; j++) o[j] = (short)f2bs(bfs2f(v[j]) * scale[c + j] + shift[c + j]);
    *(short8*)(h + base) = o;
}

// ---------------- DGI reductions (bf16 h) ----------------
__global__ __launch_bounds__(320) void colsum_k(const ushort* __restrict__ h,
                                                float* __restrict__ accum, int nrows, int F,
                                                int rpb) {
    int f = threadIdx.x;
    if (f >= F) return;
    int rs = blockIdx.x * rpb;
    int re = min(rs + rpb, nrows);
    float s = 0.f;
    for (int r = rs; r < re; r++) s += ldbs(h, (size_t)r * F + f);
    atomicAdd(&accum[f], s);
}

__global__ __launch_bounds__(320) void cfinal_k(const float* __restrict__ accum,
                                                float* __restrict__ c, float* __restrict__ cnorm,
                                                int N, int F) {
    int f = threadIdx.x;
    float v = 0.f;
    if (f < F) {
        v = accum[f] / N;
        c[f] = v;
    }
    float s2 = blockRed(v * v);
    if (threadIdx.x == 0) cnorm[0] = sqrtf(s2);
}

// MODE 0: sum += cos ; MODE 1: sum += max(cos,0)
template <int MODE>
__global__ __launch_bounds__(256) void cos_k(const ushort* __restrict__ h,
                                             const float* __restrict__ c,
                                             const float* __restrict__ cnorm,
                                             float* __restrict__ acc, int N, int F) {
    int gw = (blockIdx.x * blockDim.x + threadIdx.x) >> 6;
    int lane = threadIdx.x & 63;
    int nw = (gridDim.x * blockDim.x) >> 6;
    float cn = cnorm[0];
    float s = 0.f;
    for (int row = gw; row < N; row += nw) {
        float dot = 0.f, nsq = 0.f;
        for (int f = lane; f < F; f += 64) {
            float v = ldbs(h, (size_t)row * F + f);
            dot += v * c[f];
            nsq += v * v;
        }
#pragma unroll
        for (int o = 32; o > 0; o >>= 1) {
            dot += __shfl_down(dot, o);
            nsq += __shfl_down(nsq, o);
        }
        if (lane == 0) {
            float cosv = dot / fmaxf(sqrtf(nsq) * cn, 1e-8f);
            s += (MODE == 1) ? fmaxf(cosv, 0.f) : cosv;
        }
    }
    s = blockRed(s);
    if (threadIdx.x == 0) atomicAdd(acc, s);
}

__global__ void final_k(const float* __restrict__ lacc, void* __restrict__ dout,
                        const int* __restrict__ flagp, int SOUT, int N) {
    if (threadIdx.x == 0 && blockIdx.x == 0) {
        float loss = lacc[0] / SOUT + (1.f - lacc[1] / N) + lacc[2] / N;
        stio(dout, 0, loss, flagp[0]);
    }
}

// ---------------- launch ----------------
extern "C" void kernel_launch(void* const* d_in, const int* in_sizes, int n_in,
                              void* d_out, int out_size, void* d_ws, size_t ws_size,
                              hipStream_t stream) {
    const void* x = d_in[0];
    const void* y = d_in[1];
    const int* adj_rows = (const int*)d_in[2];
    const int* adj_cols = (const int*)d_in[3];
    const void* adj_vals = d_in[4];
    const int* agg_rows = (const int*)d_in[5];
    const void* agg_vals = d_in[6];
    const int* perm = (const int*)d_in[7];
    const void* mlp_W = d_in[8];
    const void* mlp_b = d_in[9];
    const void* bn_gamma = d_in[10];
    const void* bn_beta = d_in[11];
    const void* hg_W1 = d_in[12];
    const void* hg_b1 = d_in[13];
    const void* hg_W2 = d_in[14];
    const void* hg_b2 = d_in[15];
    const void* hg_prelu = d_in[16];
    const void* pred_W = d_in[17];
    const void* pred_b = d_in[18];
    const void* dgi_W = d_in[19];
    const void* dgi_b = d_in[20];
    const void* dgi_prelu = d_in[21];

    const int N = in_sizes[5];         // 50000
    const int NNZ = in_sizes[2];       // 800000
    const int F_IN = in_sizes[0] / N;  // 1024
    const int HID = in_sizes[9];       // 256
    const int OUT = in_sizes[18];      // 280
    const int S = in_sizes[1] / OUT;   // 5000

    // padded stride for 280-wide gather sources: 320 shorts = 640 B
    const int LDP = (OUT + 63) & ~63;  // 320 for OUT=280

    // workspace carve-up
    char* w = (char*)d_ws;
    size_t off = 0;
    auto alloc = [&](size_t b) -> char* {
        char* p = w + off;
        off += (b + 255) & ~(size_t)255;
        return p;
    };
    ushort* h0_bf = (ushort*)alloc((size_t)N * HID * 2);  // h0 (BN in place)
    ushort* U_bf = (ushort*)alloc((size_t)N * HID * 2);   // U  = S*h0
    ushort* Up_bf = (ushort*)alloc((size_t)N * HID * 2);  // U' = S*P*h0
    ushort* zA_bf = (ushort*)alloc((size_t)N * LDP * 2);  // GEMM scratch / xp (padded)
    ushort* zB_bf = (ushort*)alloc((size_t)N * LDP * 2);  // GEMM scratch / h1
    ushort* h2_bf = (ushort*)alloc((size_t)N * OUT * 2);  // DGI h2
    ushort* xp_ws = zA_bf;  // pred GEMM writes, aggmse reads
    ushort* mlpWt = (ushort*)alloc((size_t)HID * F_IN * 2);
    ushort* hgW1t = (ushort*)alloc((size_t)HID * HID * 2);
    ushort* hgW2t = (ushort*)alloc((size_t)HID * HID * 2);
    ushort* predWt = (ushort*)alloc((size_t)OUT * HID * 2);
    ushort* dgiWt = (ushort*)alloc((size_t)OUT * HID * 2);
    int* offs = (int*)alloc((size_t)(N + 1) * 4);
    int nbscan = (N + 1023) / 1024;
    int* bsums = (int*)alloc((size_t)nbscan * 4);
    int* cols_s = (int*)alloc((size_t)NNZ * 4);
    int* colsp_s = (int*)alloc((size_t)NNZ * 4);
    float* vals_s = (float*)alloc((size_t)NNZ * 4);
    int* soffs = (int*)alloc((size_t)(S + 1) * 4);
    int nbscan_s = (S + 1023) / 1024;
    int* sbsums = (int*)alloc((size_t)nbscan_s * 4);
    int* sidx = (int*)alloc((size_t)N * 4);
    float* sval = (float*)alloc((size_t)N * 4);
    float* bn_scale = (float*)alloc((size_t)HID * 4);
    float* bn_shift = (float*)alloc((size_t)HID * 4);
    float* c_vec = (float*)alloc((size_t)OUT * 4);
    float* cnorm = (float*)alloc(4);
    int* dflag = (int*)alloc(16);
    // ---- contiguous zero region (single memset) ----
    char* zero_base = w + off;
    int* counts = (int*)alloc((size_t)N * 4);
    int* cursor = (int*)alloc((size_t)N * 4);
    int* scnt = (int*)alloc((size_t)S * 4);
    int* scursor = (int*)alloc((size_t)S * 4);
    float* rsum = (float*)alloc((size_t)N * 4);  // r = S*1 (adjacency row-sums)
    float* bn_sum = (float*)alloc((size_t)HID * 4);
    float* bn_sumsq = (float*)alloc((size_t)HID * 4);
    float* c_acc = (float*)alloc((size_t)OUT * 4);
    float* lacc = (float*)alloc(16);
    size_t zero_bytes = (w + off) - zero_base;
    hipMemsetAsync(zero_base, 0, zero_bytes, stream);

    // dtype probe (dflag[0]: 1 = float32 inputs, 0 = bf16 inputs)
    probe_k<<<1, 256, 0, stream>>>(x, dflag);

    // fused weight transpose+convert
    Cvt5 cv;
    cv.src[0] = mlp_W;  cv.dst[0] = mlpWt;  cv.K[0] = F_IN; cv.N[0] = HID;
    cv.src[1] = hg_W1;  cv.dst[1] = hgW1t;  cv.K[1] = HID;  cv.N[1] = HID;
    cv.src[2] = hg_W2;  cv.dst[2] = hgW2t;  cv.K[2] = HID;  cv.N[2] = HID;
    cv.src[3] = pred_W; cv.dst[3] = predWt; cv.K[3] = HID;  cv.N[3] = OUT;
    cv.src[4] = dgi_W;  cv.dst[4] = dgiWt;  cv.K[4] = HID;  cv.N[4] = OUT;
    cvt_all_k<<<dim3((F_IN * HID + 255) / 256, 5), 256, 0, stream>>>(cv, dflag);

    // adjacency CSR (+ row-sums for the reordered bias terms)
    count_k<<<(NNZ + 255) / 256, 256, 0, stream>>>(adj_rows, counts, NNZ);
    scan_local_k<<<nbscan, 1024, 0, stream>>>(counts, offs, bsums, N);
    scan_bsums_k<<<1, 64, 0, stream>>>(bsums, nbscan);
    scan_add_k<<<(N + 255) / 256, 256, 0, stream>>>(offs, bsums, N, NNZ);
    fill_k<<<(NNZ + 255) / 256, 256, 0, stream>>>(adj_rows, adj_cols, adj_vals, perm, offs,
                                                  cursor, cols_s, colsp_s, vals_s, rsum, dflag,
                                                  NNZ);
    // agg segment CSR
    count_k<<<(N + 255) / 256, 256, 0, stream>>>(agg_rows, scnt, N);
    scan_local_k<<<nbscan_s, 1024, 0, stream>>>(scnt, soffs, sbsums, S);
    scan_bsums_k<<<1, 64, 0, stream>>>(sbsums, nbscan_s);
    scan_add_k<<<(S + 255) / 256, 256, 0, stream>>>(soffs, sbsums, S, N);
    fill_s_k<<<(N + 255) / 256, 256, 0, stream>>>(agg_rows, agg_vals, soffs, scursor, sidx, sval,
                                                  dflag, N);

    const int MT = (N + 127) / 128;
    const int NT_H = (HID + 127) / 128;  // 2
    const int NT_O = (OUT + 127) / 128;  // 3
    const int SGRID = ((N + 3) / 4) * 8;  // sliced spmm: 8 slices per row-group

    // h0 = leaky(x @ mlp_W + b, 0.1)  [MFMA]
    mgemm_k<0, 1, 0, 0><<<dim3(NT_H, MT), 256, 0, stream>>>(
        x, mlpWt, mlp_b, nullptr, nullptr, h0_bf, nullptr, dflag, N, F_IN, HID, HID);
    // BatchNorm
    bn_stats_k<<<(N + 127) / 128, HID, 0, stream>>>(h0_bf, bn_sum, bn_sumsq, N, 128);
    bn_final_k<<<1, HID, 0, stream>>>(bn_sum, bn_sumsq, bn_gamma, bn_beta, bn_scale, bn_shift,
                                      dflag, N);
    {
        int total8 = (N * HID) / 8;
        bn_apply_k<<<(total8 + 255) / 256, 256, 0, stream>>>(h0_bf, bn_scale, bn_shift, total8,
                                                             HID);
    }

    // U = S*h0 ; U' = S*P*h0  (one dual sliced spmm feeds HGNN-L1 AND both DGI streams)
    spmms_k<0, true><<<SGRID, 256, 0, stream>>>(offs, cols_s, colsp_s, vals_s, nullptr, dflag,
                                                h0_bf, U_bf, Up_bf, N, HID);

    // t1 = prelu(U @ W1 + r*b1)   [reordered: S(XW+1b^T) = (SX)W + r(x)b]
    mgemm_k<1, 3, 0, 1><<<dim3(NT_H, MT), 256, 0, stream>>>(
        U_bf, hgW1t, hg_b1, rsum, hg_prelu, zB_bf, nullptr, dflag, N, HID, HID, HID);
    // z2 = t1 @ W2 + b2
    mgemm_k<1, 0, 0, 0><<<dim3(NT_H, MT), 256, 0, stream>>>(
        zB_bf, hgW2t, hg_b2, nullptr, nullptr, zA_bf, nullptr, dflag, N, HID, HID, HID);
    // t2 = leaky(S*z2, 0.01)  (sliced spmm)
    spmms_k<2, false><<<SGRID, 256, 0, stream>>>(offs, cols_s, nullptr, vals_s, nullptr, dflag,
                                                 zA_bf, zB_bf, nullptr, N, HID);

    // x_prime -> d_out[1:] (flag dtype) + aligned bf16 copy (padded stride)
    mgemm_k<1, 2, 1, 0><<<dim3(NT_O, MT), 256, 0, stream>>>(
        zB_bf, predWt, pred_b, nullptr, nullptr, d_out, xp_ws, dflag, N, HID, OUT, LDP);
    // fused agg segment-sum + MSE
    aggmse_k<<<(S + 3) / 4, 256, 0, stream>>>(soffs, sidx, sval, xp_ws, y, dflag, lacc, S, OUT,
                                              LDP);

    // DGI: h1 = prelu(U @ dgiW + r*b) ; h2 = prelu(U' @ dgiW + r*b)
    mgemm_k<1, 3, 0, 1><<<dim3(NT_O, MT), 256, 0, stream>>>(
        U_bf, dgiWt, dgi_b, rsum, dgi_prelu, zB_bf, nullptr, dflag, N, HID, OUT, OUT);
    mgemm_k<1, 3, 0, 1><<<dim3(NT_O, MT), 256, 0, stream>>>(
        Up_bf, dgiWt, dgi_b, rsum, dgi_prelu, h2_bf, nullptr, dflag, N, HID, OUT, OUT);

    colsum_k<<<(N + 127) / 128, 320, 0, stream>>>(zB_bf, c_acc, N, OUT, 128);
    cfinal_k<<<1, 320, 0, stream>>>(c_acc, c_vec, cnorm, N, OUT);
    cos_k<0><<<256, 256, 0, stream>>>(zB_bf, c_vec, cnorm, &lacc[1], N, OUT);
    cos_k<1><<<256, 256, 0, stream>>>(h2_bf, c_vec, cnorm, &lacc[2], N, OUT);

    final_k<<<1, 64, 0, stream>>>(lacc, d_out, dflag, S * OUT, N);
}

// Round 4
// 1201.476 us; speedup vs baseline: 1.2381x; 1.2381x over previous
//
#include <hip/hip_runtime.h>
#include <hip/hip_bf16.h>

#define DEVI __device__ __forceinline__

typedef __attribute__((ext_vector_type(8))) short short8;
typedef __attribute__((ext_vector_type(4))) float float4v;

DEVI float bf2f(__hip_bfloat16 v) { return __bfloat162float(v); }
DEVI float ldbs(const ushort* p, size_t i) { return bf2f(((const __hip_bfloat16*)p)[i]); }
DEVI ushort f2bs(float v) {
    __hip_bfloat16 h = __float2bfloat16(v);
    return *(ushort*)&h;
}
DEVI float bfs2f(short s) {
    ushort u = (ushort)s;
    return bf2f(*(__hip_bfloat16*)&u);
}

// flag-dependent element load/store: isf32 selects float32 vs bf16 view
DEVI float ldin(const void* p, size_t i, int isf32) {
    return isf32 ? ((const float*)p)[i] : bf2f(((const __hip_bfloat16*)p)[i]);
}
DEVI void stio(void* p, size_t i, float v, int isf32) {
    if (isf32) ((float*)p)[i] = v;
    else ((ushort*)p)[i] = f2bs(v);
}

// ACT: 0 none, 1 leaky(0.1), 2 leaky(0.01), 3 prelu(alpha)
template <int ACT>
DEVI float act_fn(float v, float alpha) {
    if (ACT == 1) return v >= 0.f ? v : 0.1f * v;
    if (ACT == 2) return v >= 0.f ? v : 0.01f * v;
    if (ACT == 3) return v >= 0.f ? v : alpha * v;
    return v;
}

DEVI float waveRed(float v) {
#pragma unroll
    for (int o = 32; o > 0; o >>= 1) v += __shfl_down(v, o);
    return v;
}

DEVI float blockRed(float v) {
    __shared__ float sm[16];
    int lane = threadIdx.x & 63, w = threadIdx.x >> 6;
    v = waveRed(v);
    if (lane == 0) sm[w] = v;
    __syncthreads();
    if (w == 0) {
        int nw = (blockDim.x + 63) >> 6;
        v = (lane < nw) ? sm[lane] : 0.f;
        v = waveRed(v);
    }
    return v;  // valid on thread 0
}

// ---------------- dtype probe ----------------
__global__ void probe_k(const void* __restrict__ x, int* __restrict__ flag) {
    __shared__ int sfails;
    int t = threadIdx.x;
    if (t == 0) sfails = 0;
    __syncthreads();
    const __hip_bfloat16* xb = (const __hip_bfloat16*)x;
    int my = 0;
    for (int i = t; i < 4096; i += 256) {
        float v = bf2f(xb[i]);
        float a = fabsf(v);
        if (!(a <= 64.f) || (v != 0.f && a < 1e-6f)) my++;
    }
    atomicAdd(&sfails, my);
    __syncthreads();
    if (t == 0) flag[0] = (sfails > 409) ? 1 : 0;  // >10% fail => inputs are float32
}

// ---------------- fused weight transpose+convert (5 weights in one launch) ----
struct Cvt5 {
    const void* src[5];
    ushort* dst[5];
    int K[5];
    int N[5];
};
__global__ void cvt_all_k(Cvt5 d, const int* __restrict__ flagp) {
    int f32 = flagp[0];
    int seg = blockIdx.y;
    int idx = blockIdx.x * blockDim.x + threadIdx.x;
    int K = d.K[seg], Nc = d.N[seg];
    int total = K * Nc;
    if (idx < total) {
        int k = idx / Nc, n = idx % Nc;
        d.dst[seg][(size_t)n * K + k] = f2bs(ldin(d.src[seg], idx, f32));
    }
}

// ---------------- MFMA bf16 GEMM ----------------
// C[M][Nc] = act(A[M][K] @ Bt[Nc][K]^T + bias_eff)
// 128x128 tile, 256 threads (4 waves 2x2), 16x16x32 MFMA, BK=32, pitch 40 shorts.
// Grid is (NT, MT): N-tiles fastest for A-panel L2 reuse.
// Issue/commit staging split with 1-tile register prefetch (R2 win).
// AMODE: 0 = A is flag-typed model input, 1 = A is bf16 workspace
// OMODE: 0 = out bf16 ws (stride LDo); 1 = d_out (flag-typed,+1) AND outp2 bf16 ws
// BMODE: 0 = bias[n]; 1 = rsc[m]*bias[n]  (row-scaled bias for spmm-reordered path)
#define TP 40
template <int AMODE, int ACT, int OMODE, int BMODE>
__global__ __launch_bounds__(256) void mgemm_k(
    const void* __restrict__ A, const ushort* __restrict__ Bt,
    const void* __restrict__ bias, const float* __restrict__ rsc,
    const void* __restrict__ alpha_p, void* __restrict__ outp, ushort* __restrict__ outp2,
    const int* __restrict__ flagp, int M, int K, int Nc, int LDo) {
    __shared__ short As[128 * TP];
    __shared__ short Bs[128 * TP];
    const int f32 = flagp[0];
    const int tid = threadIdx.x;
    const int lane = tid & 63;
    const int l15 = lane & 15;
    const int quad = lane >> 4;
    const int wid = tid >> 6;
    const int mW = (wid >> 1) * 64;
    const int nW = (wid & 1) * 64;
    const int mBase = blockIdx.y * 128;
    const int nBase = blockIdx.x * 128;

    float4v acc[4][4];
#pragma unroll
    for (int i = 0; i < 4; i++)
#pragma unroll
        for (int j = 0; j < 4; j++) acc[i][j] = (float4v){0.f, 0.f, 0.f, 0.f};

    // staging registers (raw bits; converted at commit)
    short8 sa[2], sb[2];
    float4v fa[2][2];

    auto issue_tile = [&](int k0) {
#pragma unroll
        for (int i = 0; i < 2; i++) {
            int chunk = i * 256 + tid;
            int row = chunk >> 2;
            int c = chunk & 3;
            int gr = mBase + row;
            int gn = nBase + row;
            size_t geA = (size_t)gr * K + k0 + c * 8;
            if (AMODE == 0 && f32) {
                if (gr < M) {
                    const float* af = (const float*)A + geA;
                    fa[i][0] = *(const float4v*)af;
                    fa[i][1] = *(const float4v*)(af + 4);
                } else {
                    fa[i][0] = (float4v){0.f, 0.f, 0.f, 0.f};
                    fa[i][1] = (float4v){0.f, 0.f, 0.f, 0.f};
                }
            } else {
                sa[i] = (gr < M) ? *(const short8*)((const ushort*)A + geA)
                                 : (short8){0, 0, 0, 0, 0, 0, 0, 0};
            }
            sb[i] = (gn < Nc) ? *(const short8*)(Bt + (size_t)gn * K + k0 + c * 8)
                              : (short8){0, 0, 0, 0, 0, 0, 0, 0};
        }
    };

    auto commit_tile = [&]() {
#pragma unroll
        for (int i = 0; i < 2; i++) {
            int chunk = i * 256 + tid;
            int row = chunk >> 2;
            int c = chunk & 3;
            short8 va;
            if (AMODE == 0 && f32) {
#pragma unroll
                for (int j = 0; j < 4; j++) va[j] = (short)f2bs(fa[i][0][j]);
#pragma unroll
                for (int j = 0; j < 4; j++) va[4 + j] = (short)f2bs(fa[i][1][j]);
            } else {
                va = sa[i];
            }
            *(short8*)&As[row * TP + c * 8] = va;
            *(short8*)&Bs[row * TP + c * 8] = sb[i];
        }
    };

    const int nk = K >> 5;
    issue_tile(0);
    for (int t = 0; t < nk; ++t) {
        __syncthreads();  // previous tile's readers done
        commit_tile();    // vmcnt wait lands here (issue was a full phase ago)
        if (t + 1 < nk) issue_tile((t + 1) << 5);  // in flight across barrier+compute
        __syncthreads();  // LDS tile ready

        short8 af[4], bf[4];
#pragma unroll
        for (int i = 0; i < 4; i++)
            af[i] = *(const short8*)&As[(mW + i * 16 + l15) * TP + quad * 8];
#pragma unroll
        for (int j = 0; j < 4; j++)
            bf[j] = *(const short8*)&Bs[(nW + j * 16 + l15) * TP + quad * 8];
#pragma unroll
        for (int i = 0; i < 4; i++)
#pragma unroll
            for (int j = 0; j < 4; j++)
                acc[i][j] =
                    __builtin_amdgcn_mfma_f32_16x16x32_bf16(af[i], bf[j], acc[i][j], 0, 0, 0);
    }

    const float alpha = (ACT == 3) ? ldin(alpha_p, 0, f32) : 0.f;
#pragma unroll
    for (int i = 0; i < 4; i++) {
#pragma unroll
        for (int j = 0; j < 4; j++) {
            int gcn = nBase + nW + j * 16 + l15;
            if (gcn >= Nc) continue;
            float bv = ldin(bias, gcn, f32);
#pragma unroll
            for (int r = 0; r < 4; r++) {
                int grm = mBase + mW + i * 16 + quad * 4 + r;
                if (grm >= M) continue;
                float be = (BMODE == 1) ? rsc[grm] * bv : bv;
                float v = act_fn<ACT>(acc[i][j][r] + be, alpha);
                if (OMODE == 1) {
                    stio(outp, 1 + (size_t)grm * Nc + gcn, v, f32);
                    outp2[(size_t)grm * LDo + gcn] = f2bs(v);
                } else {
                    ((ushort*)outp)[(size_t)grm * LDo + gcn] = f2bs(v);
                }
            }
        }
    }
}

// ---------------- CSR build (generic: used for adjacency and agg segments) ---
__global__ void count_k(const int* __restrict__ rows, int* __restrict__ counts, int nnz) {
    int i = blockIdx.x * blockDim.x + threadIdx.x;
    if (i < nnz) atomicAdd(&counts[rows[i]], 1);
}

__global__ __launch_bounds__(1024) void scan_local_k(const int* __restrict__ counts,
                                                     int* __restrict__ offs,
                                                     int* __restrict__ bsums, int n) {
    __shared__ int sm[1024];
    int t = threadIdx.x;
    int g = blockIdx.x * 1024 + t;
    int v = (g < n) ? counts[g] : 0;
    sm[t] = v;
    __syncthreads();
    for (int d = 1; d < 1024; d <<= 1) {
        int add = (t >= d) ? sm[t - d] : 0;
        __syncthreads();
        sm[t] += add;
        __syncthreads();
    }
    if (g < n) offs[g] = sm[t] - v;  // exclusive
    if (t == 1023) bsums[blockIdx.x] = sm[t];
}

__global__ void scan_bsums_k(int* bsums, int nb) {
    if (threadIdx.x == 0 && blockIdx.x == 0) {
        int acc = 0;
        for (int i = 0; i < nb; i++) {
            int v = bsums[i];
            bsums[i] = acc;
            acc += v;
        }
    }
}

__global__ void scan_add_k(int* __restrict__ offs, const int* __restrict__ bsums, int n, int nnz) {
    int g = blockIdx.x * blockDim.x + threadIdx.x;
    if (g < n) offs[g] += bsums[g >> 10];
    if (g == 0) offs[n] = nnz;
}

// adjacency fill: pre-applies perm for colsp; accumulates row-sums r = S*1
__global__ void fill_k(const int* __restrict__ rows, const int* __restrict__ cols,
                       const void* __restrict__ vals, const int* __restrict__ perm,
                       const int* __restrict__ offs, int* __restrict__ cursor,
                       int* __restrict__ cols_s, int* __restrict__ colsp_s,
                       float* __restrict__ vals_s, float* __restrict__ rsum,
                       const int* __restrict__ flagp, int nnz) {
    int e = blockIdx.x * blockDim.x + threadIdx.x;
    if (e < nnz) {
        int r = rows[e];
        int pos = offs[r] + atomicAdd(&cursor[r], 1);
        int c = cols[e];
        float v = ldin(vals, e, flagp[0]);
        cols_s[pos] = c;
        colsp_s[pos] = perm[c];
        vals_s[pos] = v;
        atomicAdd(&rsum[r], v);
    }
}

// agg segment fill (source index = element position)
__global__ void fill_s_k(const int* __restrict__ rows, const void* __restrict__ vals,
                         const int* __restrict__ offs, int* __restrict__ cursor,
                         int* __restrict__ idx_s, float* __restrict__ val_s,
                         const int* __restrict__ flagp, int n) {
    int e = blockIdx.x * blockDim.x + threadIdx.x;
    if (e < n) {
        int r = rows[e];
        int pos = offs[r] + atomicAdd(&cursor[r], 1);
        idx_s[pos] = e;
        val_s[pos] = ldin(vals, e, flagp[0]);
    }
}

// ---------------- vectorized SpMM, F=256 specialized ----------------
// One wave per dest row: 32 lanes x 16 B = exactly one 512 B source row.
// half = lane>>5 processes edges s+half, s+half+2, ...; l5 = lane&31 owns chunk l5.
// DEPTH=4 software pipeline: 4 edges' (col,val) staged, then 4 (8 if DUAL)
// 16 B gathers issued before any accumulate.
// DUAL: second gather stream via colsp (perm) into out2.
// EPI: 0 = act_fn<ACT>; 1 = fused BatchNorm affine on the REORDERED form:
//      out = scale[f]*acc + rsum[row]*shift[f]   (S*(h*sc+1(x)sh) = (S*h)sc + r(x)sh)
template <int ACT, bool DUAL, int EPI>
__global__ __launch_bounds__(256) void spmmv_k(
    const int* __restrict__ offs, const int* __restrict__ cols_s,
    const int* __restrict__ colsp_s, const float* __restrict__ vals_s,
    const void* __restrict__ alpha_p, const int* __restrict__ flagp,
    const ushort* __restrict__ Min, ushort* __restrict__ out1, ushort* __restrict__ out2,
    const float* __restrict__ scale, const float* __restrict__ shift,
    const float* __restrict__ rsum, int Nrow) {
    const int LD = 256;
    int row = blockIdx.x * 4 + (threadIdx.x >> 6);
    if (row >= Nrow) return;
    int lane = threadIdx.x & 63;
    int half = lane >> 5, l5 = lane & 31;
    int sbase = l5 * 8;
    float alpha = (ACT == 3) ? ldin(alpha_p, 0, flagp[0]) : 0.f;
    int s = offs[row], e = offs[row + 1];
    float a[8] = {}, b[8] = {};

    constexpr int DEPTH = 4;
    int i = s + half;
    for (; i + 2 * (DEPTH - 1) < e; i += 2 * DEPTH) {
        int c[DEPTH];
        float v[DEPTH];
        int cp[DEPTH];
#pragma unroll
        for (int u = 0; u < DEPTH; u++) {
            c[u] = cols_s[i + 2 * u];
            v[u] = vals_s[i + 2 * u];
        }
        if (DUAL) {
#pragma unroll
            for (int u = 0; u < DEPTH; u++) cp[u] = colsp_s[i + 2 * u];
        }
        short8 hv[DEPTH], gv[DEPTH];
#pragma unroll
        for (int u = 0; u < DEPTH; u++) {
            hv[u] = *(const short8*)(Min + (size_t)c[u] * LD + sbase);
            if (DUAL) gv[u] = *(const short8*)(Min + (size_t)cp[u] * LD + sbase);
        }
#pragma unroll
        for (int u = 0; u < DEPTH; u++) {
#pragma unroll
            for (int j = 0; j < 8; j++) a[j] += v[u] * bfs2f(hv[u][j]);
            if (DUAL) {
#pragma unroll
                for (int j = 0; j < 8; j++) b[j] += v[u] * bfs2f(gv[u][j]);
            }
        }
    }
    for (; i < e; i += 2) {
        float v = vals_s[i];
        int c = cols_s[i];
        short8 h = *(const short8*)(Min + (size_t)c * LD + sbase);
#pragma unroll
        for (int j = 0; j < 8; j++) a[j] += v * bfs2f(h[j]);
        if (DUAL) {
            int cp = colsp_s[i];
            short8 g = *(const short8*)(Min + (size_t)cp * LD + sbase);
#pragma unroll
            for (int j = 0; j < 8; j++) b[j] += v * bfs2f(g[j]);
        }
    }
#pragma unroll
    for (int j = 0; j < 8; j++) {
        a[j] += __shfl_xor(a[j], 32);
        if (DUAL) b[j] += __shfl_xor(b[j], 32);
    }
    if (half == 0) {
        size_t obase = (size_t)row * LD + sbase;
        short8 o;
        if (EPI == 1) {
            float4v sc0 = *(const float4v*)(scale + sbase);
            float4v sc1 = *(const float4v*)(scale + sbase + 4);
            float4v sh0 = *(const float4v*)(shift + sbase);
            float4v sh1 = *(const float4v*)(shift + sbase + 4);
            float rr = rsum[row];
#pragma unroll
            for (int j = 0; j < 4; j++) o[j] = (short)f2bs(sc0[j] * a[j] + rr * sh0[j]);
#pragma unroll
            for (int j = 0; j < 4; j++) o[4 + j] = (short)f2bs(sc1[j] * a[4 + j] + rr * sh1[j]);
            *(short8*)(out1 + obase) = o;
            if (DUAL) {
#pragma unroll
                for (int j = 0; j < 4; j++) o[j] = (short)f2bs(sc0[j] * b[j] + rr * sh0[j]);
#pragma unroll
                for (int j = 0; j < 4; j++)
                    o[4 + j] = (short)f2bs(sc1[j] * b[4 + j] + rr * sh1[j]);
                *(short8*)(out2 + obase) = o;
            }
        } else {
#pragma unroll
            for (int j = 0; j < 8; j++) o[j] = (short)f2bs(act_fn<ACT>(a[j], alpha));
            *(short8*)(out1 + obase) = o;
            if (DUAL) {
#pragma unroll
                for (int j = 0; j < 8; j++) o[j] = (short)f2bs(act_fn<ACT>(b[j], alpha));
                *(short8*)(out2 + obase) = o;
            }
        }
    }
}

// ---------------- fused agg segment-sum + MSE (gather, no atomics on agg) ----
__global__ __launch_bounds__(256) void aggmse_k(
    const int* __restrict__ soffs, const int* __restrict__ sidx, const float* __restrict__ sval,
    const ushort* __restrict__ xp, const void* __restrict__ y, const int* __restrict__ flagp,
    float* __restrict__ lacc, int S, int F, int LDxp) {
    int srow = blockIdx.x * 4 + (threadIdx.x >> 6);
    int lane = threadIdx.x & 63;
    int half = lane >> 5, l5 = lane & 31;
    int FC = F >> 3;
    bool has1 = (l5 + 32) < FC;
    float a0[8] = {}, a1[8] = {};
    if (srow < S) {
        int s = soffs[srow], e = soffs[srow + 1];
        constexpr int DEPTH = 4;
        int i = s + half;
        for (; i + 2 * (DEPTH - 1) < e; i += 2 * DEPTH) {
            int n[DEPTH];
            float v[DEPTH];
#pragma unroll
            for (int u = 0; u < DEPTH; u++) {
                n[u] = sidx[i + 2 * u];
                v[u] = sval[i + 2 * u];
            }
            short8 h0v[DEPTH], h1v[DEPTH];
#pragma unroll
            for (int u = 0; u < DEPTH; u++) {
                const ushort* src = xp + (size_t)n[u] * LDxp;
                h0v[u] = *(const short8*)(src + l5 * 8);
                if (has1) h1v[u] = *(const short8*)(src + (l5 + 32) * 8);
            }
#pragma unroll
            for (int u = 0; u < DEPTH; u++) {
#pragma unroll
                for (int j = 0; j < 8; j++) a0[j] += v[u] * bfs2f(h0v[u][j]);
                if (has1) {
#pragma unroll
                    for (int j = 0; j < 8; j++) a1[j] += v[u] * bfs2f(h1v[u][j]);
                }
            }
        }
        for (; i < e; i += 2) {
            float v = sval[i];
            int n = sidx[i];
            const ushort* src = xp + (size_t)n * LDxp;
            short8 h = *(const short8*)(src + l5 * 8);
#pragma unroll
            for (int j = 0; j < 8; j++) a0[j] += v * bfs2f(h[j]);
            if (has1) {
                short8 h2 = *(const short8*)(src + (l5 + 32) * 8);
#pragma unroll
                for (int j = 0; j < 8; j++) a1[j] += v * bfs2f(h2[j]);
            }
        }
    }
#pragma unroll
    for (int j = 0; j < 8; j++) {
        a0[j] += __shfl_xor(a0[j], 32);
        if (has1) a1[j] += __shfl_xor(a1[j], 32);
    }
    float ss = 0.f;
    if (srow < S && half == 0) {
        int f32 = flagp[0];
        size_t base = (size_t)srow * F;
#pragma unroll
        for (int j = 0; j < 8; j++) {
            float d = a0[j] - ldin(y, base + l5 * 8 + j, f32);
            ss += d * d;
        }
        if (has1) {
#pragma unroll
            for (int j = 0; j < 8; j++) {
                float d = a1[j] - ldin(y, base + (l5 + 32) * 8 + j, f32);
                ss += d * d;
            }
        }
    }
    ss = blockRed(ss);
    if (threadIdx.x == 0) atomicAdd(&lacc[0], ss);
}

// ---------------- BatchNorm stats (apply is fused into the dual spmm) --------
__global__ __launch_bounds__(256) void bn_stats_k(const ushort* __restrict__ h,
                                                  float* __restrict__ sum,
                                                  float* __restrict__ sumsq, int nrows, int rpb) {
    int c = threadIdx.x;
    int rs = blockIdx.x * rpb;
    int re = min(rs + rpb, nrows);
    float s = 0.f, s2 = 0.f;
    int H = blockDim.x;
    for (int r = rs; r < re; r++) {
        float v = ldbs(h, (size_t)r * H + c);
        s += v;
        s2 += v * v;
    }
    atomicAdd(&sum[c], s);
    atomicAdd(&sumsq[c], s2);
}

__global__ void bn_final_k(const float* __restrict__ sum, const float* __restrict__ sumsq,
                           const void* __restrict__ gamma, const void* __restrict__ beta,
                           float* __restrict__ scale, float* __restrict__ shift,
                           const int* __restrict__ flagp, int nrows) {
    int c = threadIdx.x;
    int f32 = flagp[0];
    float mu = sum[c] / nrows;
    float var = sumsq[c] / nrows - mu * mu;
    float sc = ldin(gamma, c, f32) * rsqrtf(var + 1e-5f);
    scale[c] = sc;
    shift[c] = ldin(beta, c, f32) - mu * sc;
}

// ---------------- DGI reductions (bf16 h) ----------------
__global__ __launch_bounds__(320) void colsum_k(const ushort* __restrict__ h,
                                                float* __restrict__ accum, int nrows, int F,
                                                int rpb) {
    int f = threadIdx.x;
    if (f >= F) return;
    int rs = blockIdx.x * rpb;
    int re = min(rs + rpb, nrows);
    float s = 0.f;
    for (int r = rs; r < re; r++) s += ldbs(h, (size_t)r * F + f);
    atomicAdd(&accum[f], s);
}

__global__ __launch_bounds__(320) void cfinal_k(const float* __restrict__ accum,
                                                float* __restrict__ c, float* __restrict__ cnorm,
                                                int N, int F) {
    int f = threadIdx.x;
    float v = 0.f;
    if (f < F) {
        v = accum[f] / N;
        c[f] = v;
    }
    float s2 = blockRed(v * v);
    if (threadIdx.x == 0) cnorm[0] = sqrtf(s2);
}

// MODE 0: sum += cos ; MODE 1: sum += max(cos,0)
template <int MODE>
__global__ __launch_bounds__(256) void cos_k(const ushort* __restrict__ h,
                                             const float* __restrict__ c,
                                             const float* __restrict__ cnorm,
                                             float* __restrict__ acc, int N, int F) {
    int gw = (blockIdx.x * blockDim.x + threadIdx.x) >> 6;
    int lane = threadIdx.x & 63;
    int nw = (gridDim.x * blockDim.x) >> 6;
    float cn = cnorm[0];
    float s = 0.f;
    for (int row = gw; row < N; row += nw) {
        float dot = 0.f, nsq = 0.f;
        for (int f = lane; f < F; f += 64) {
            float v = ldbs(h, (size_t)row * F + f);
            dot += v * c[f];
            nsq += v * v;
        }
#pragma unroll
        for (int o = 32; o > 0; o >>= 1) {
            dot += __shfl_down(dot, o);
            nsq += __shfl_down(nsq, o);
        }
        if (lane == 0) {
            float cosv = dot / fmaxf(sqrtf(nsq) * cn, 1e-8f);
            s += (MODE == 1) ? fmaxf(cosv, 0.f) : cosv;
        }
    }
    s = blockRed(s);
    if (threadIdx.x == 0) atomicAdd(acc, s);
}

__global__ void final_k(const float* __restrict__ lacc, void* __restrict__ dout,
                        const int* __restrict__ flagp, int SOUT, int N) {
    if (threadIdx.x == 0 && blockIdx.x == 0) {
        float loss = lacc[0] / SOUT + (1.f - lacc[1] / N) + lacc[2] / N;
        stio(dout, 0, loss, flagp[0]);
    }
}

// ---------------- launch ----------------
extern "C" void kernel_launch(void* const* d_in, const int* in_sizes, int n_in,
                              void* d_out, int out_size, void* d_ws, size_t ws_size,
                              hipStream_t stream) {
    const void* x = d_in[0];
    const void* y = d_in[1];
    const int* adj_rows = (const int*)d_in[2];
    const int* adj_cols = (const int*)d_in[3];
    const void* adj_vals = d_in[4];
    const int* agg_rows = (const int*)d_in[5];
    const void* agg_vals = d_in[6];
    const int* perm = (const int*)d_in[7];
    const void* mlp_W = d_in[8];
    const void* mlp_b = d_in[9];
    const void* bn_gamma = d_in[10];
    const void* bn_beta = d_in[11];
    const void* hg_W1 = d_in[12];
    const void* hg_b1 = d_in[13];
    const void* hg_W2 = d_in[14];
    const void* hg_b2 = d_in[15];
    const void* hg_prelu = d_in[16];
    const void* pred_W = d_in[17];
    const void* pred_b = d_in[18];
    const void* dgi_W = d_in[19];
    const void* dgi_b = d_in[20];
    const void* dgi_prelu = d_in[21];

    const int N = in_sizes[5];         // 50000
    const int NNZ = in_sizes[2];       // 800000
    const int F_IN = in_sizes[0] / N;  // 1024
    const int HID = in_sizes[9];       // 256
    const int OUT = in_sizes[18];      // 280
    const int S = in_sizes[1] / OUT;   // 5000

    // padded stride for 280-wide gather sources: 320 shorts = 640 B
    const int LDP = (OUT + 63) & ~63;  // 320 for OUT=280

    // workspace carve-up
    char* w = (char*)d_ws;
    size_t off = 0;
    auto alloc = [&](size_t b) -> char* {
        char* p = w + off;
        off += (b + 255) & ~(size_t)255;
        return p;
    };
    ushort* h0_bf = (ushort*)alloc((size_t)N * HID * 2);  // h0 pre-BN (BN fused into spmm)
    ushort* U_bf = (ushort*)alloc((size_t)N * HID * 2);   // U  = S*h0_bn
    ushort* Up_bf = (ushort*)alloc((size_t)N * HID * 2);  // U' = S*P*h0_bn
    ushort* zA_bf = (ushort*)alloc((size_t)N * LDP * 2);  // GEMM scratch / xp (padded)
    ushort* zB_bf = (ushort*)alloc((size_t)N * LDP * 2);  // GEMM scratch / h1
    ushort* h2_bf = (ushort*)alloc((size_t)N * OUT * 2);  // DGI h2
    ushort* xp_ws = zA_bf;  // pred GEMM writes, aggmse reads
    ushort* mlpWt = (ushort*)alloc((size_t)HID * F_IN * 2);
    ushort* hgW1t = (ushort*)alloc((size_t)HID * HID * 2);
    ushort* hgW2t = (ushort*)alloc((size_t)HID * HID * 2);
    ushort* predWt = (ushort*)alloc((size_t)OUT * HID * 2);
    ushort* dgiWt = (ushort*)alloc((size_t)OUT * HID * 2);
    int* offs = (int*)alloc((size_t)(N + 1) * 4);
    int nbscan = (N + 1023) / 1024;
    int* bsums = (int*)alloc((size_t)nbscan * 4);
    int* cols_s = (int*)alloc((size_t)NNZ * 4);
    int* colsp_s = (int*)alloc((size_t)NNZ * 4);
    float* vals_s = (float*)alloc((size_t)NNZ * 4);
    int* soffs = (int*)alloc((size_t)(S + 1) * 4);
    int nbscan_s = (S + 1023) / 1024;
    int* sbsums = (int*)alloc((size_t)nbscan_s * 4);
    int* sidx = (int*)alloc((size_t)N * 4);
    float* sval = (float*)alloc((size_t)N * 4);
    float* bn_scale = (float*)alloc((size_t)HID * 4);
    float* bn_shift = (float*)alloc((size_t)HID * 4);
    float* c_vec = (float*)alloc((size_t)OUT * 4);
    float* cnorm = (float*)alloc(4);
    int* dflag = (int*)alloc(16);
    // ---- contiguous zero region (single memset) ----
    char* zero_base = w + off;
    int* counts = (int*)alloc((size_t)N * 4);
    int* cursor = (int*)alloc((size_t)N * 4);
    int* scnt = (int*)alloc((size_t)S * 4);
    int* scursor = (int*)alloc((size_t)S * 4);
    float* rsum = (float*)alloc((size_t)N * 4);  // r = S*1 (adjacency row-sums)
    float* bn_sum = (float*)alloc((size_t)HID * 4);
    float* bn_sumsq = (float*)alloc((size_t)HID * 4);
    float* c_acc = (float*)alloc((size_t)OUT * 4);
    float* lacc = (float*)alloc(16);
    size_t zero_bytes = (w + off) - zero_base;
    hipMemsetAsync(zero_base, 0, zero_bytes, stream);

    // dtype probe (dflag[0]: 1 = float32 inputs, 0 = bf16 inputs)
    probe_k<<<1, 256, 0, stream>>>(x, dflag);

    // fused weight transpose+convert
    Cvt5 cv;
    cv.src[0] = mlp_W;  cv.dst[0] = mlpWt;  cv.K[0] = F_IN; cv.N[0] = HID;
    cv.src[1] = hg_W1;  cv.dst[1] = hgW1t;  cv.K[1] = HID;  cv.N[1] = HID;
    cv.src[2] = hg_W2;  cv.dst[2] = hgW2t;  cv.K[2] = HID;  cv.N[2] = HID;
    cv.src[3] = pred_W; cv.dst[3] = predWt; cv.K[3] = HID;  cv.N[3] = OUT;
    cv.src[4] = dgi_W;  cv.dst[4] = dgiWt;  cv.K[4] = HID;  cv.N[4] = OUT;
    cvt_all_k<<<dim3((F_IN * HID + 255) / 256, 5), 256, 0, stream>>>(cv, dflag);

    // adjacency CSR (+ row-sums for the reordered bias terms)
    count_k<<<(NNZ + 255) / 256, 256, 0, stream>>>(adj_rows, counts, NNZ);
    scan_local_k<<<nbscan, 1024, 0, stream>>>(counts, offs, bsums, N);
    scan_bsums_k<<<1, 64, 0, stream>>>(bsums, nbscan);
    scan_add_k<<<(N + 255) / 256, 256, 0, stream>>>(offs, bsums, N, NNZ);
    fill_k<<<(NNZ + 255) / 256, 256, 0, stream>>>(adj_rows, adj_cols, adj_vals, perm, offs,
                                                  cursor, cols_s, colsp_s, vals_s, rsum, dflag,
                                                  NNZ);
    // agg segment CSR
    count_k<<<(N + 255) / 256, 256, 0, stream>>>(agg_rows, scnt, N);
    scan_local_k<<<nbscan_s, 1024, 0, stream>>>(scnt, soffs, sbsums, S);
    scan_bsums_k<<<1, 64, 0, stream>>>(sbsums, nbscan_s);
    scan_add_k<<<(S + 255) / 256, 256, 0, stream>>>(soffs, sbsums, S, N);
    fill_s_k<<<(N + 255) / 256, 256, 0, stream>>>(agg_rows, agg_vals, soffs, scursor, sidx, sval,
                                                  dflag, N);

    const int MT = (N + 127) / 128;
    const int NT_H = (HID + 127) / 128;   // 2
    const int NT_O = (OUT + 127) / 128;   // 3
    const int SPB = (N + 3) / 4;          // spmm blocks (4 rows each)

    // h0 = leaky(x @ mlp_W + b, 0.1)  [MFMA]   (pre-BN; BN applied in spmm epi)
    mgemm_k<0, 1, 0, 0><<<dim3(NT_H, MT), 256, 0, stream>>>(
        x, mlpWt, mlp_b, nullptr, nullptr, h0_bf, nullptr, dflag, N, F_IN, HID, HID);
    // BatchNorm stats -> scale/shift
    bn_stats_k<<<(N + 127) / 128, HID, 0, stream>>>(h0_bf, bn_sum, bn_sumsq, N, 128);
    bn_final_k<<<1, HID, 0, stream>>>(bn_sum, bn_sumsq, bn_gamma, bn_beta, bn_scale, bn_shift,
                                      dflag, N);

    // U = S*h0_bn ; U' = S*P*h0_bn  (dual spmm; BN affine fused in epilogue:
    //   S*(h*sc + 1(x)sh) = (S*h)*sc + rsum(x)sh, and S*P*1 = S*1 = rsum)
    spmmv_k<0, true, 1><<<SPB, 256, 0, stream>>>(offs, cols_s, colsp_s, vals_s, nullptr, dflag,
                                                 h0_bf, U_bf, Up_bf, bn_scale, bn_shift, rsum, N);

    // t1 = prelu(U @ W1 + rsum*b1)   [reordered: S(XW+1b^T) = (SX)W + r(x)b]
    mgemm_k<1, 3, 0, 1><<<dim3(NT_H, MT), 256, 0, stream>>>(
        U_bf, hgW1t, hg_b1, rsum, hg_prelu, zB_bf, nullptr, dflag, N, HID, HID, HID);
    // z2 = t1 @ W2 + b2
    mgemm_k<1, 0, 0, 0><<<dim3(NT_H, MT), 256, 0, stream>>>(
        zB_bf, hgW2t, hg_b2, nullptr, nullptr, zA_bf, nullptr, dflag, N, HID, HID, HID);
    // t2 = leaky(S*z2, 0.01)
    spmmv_k<2, false, 0><<<SPB, 256, 0, stream>>>(offs, cols_s, nullptr, vals_s, nullptr, dflag,
                                                  zA_bf, zB_bf, nullptr, nullptr, nullptr,
                                                  nullptr, N);

    // x_prime -> d_out[1:] (flag dtype) + aligned bf16 copy (padded stride)
    mgemm_k<1, 2, 1, 0><<<dim3(NT_O, MT), 256, 0, stream>>>(
        zB_bf, predWt, pred_b, nullptr, nullptr, d_out, xp_ws, dflag, N, HID, OUT, LDP);
    // fused agg segment-sum + MSE
    aggmse_k<<<(S + 3) / 4, 256, 0, stream>>>(soffs, sidx, sval, xp_ws, y, dflag, lacc, S, OUT,
                                              LDP);

    // DGI: h1 = prelu(U @ dgiW + rsum*b) ; h2 = prelu(U' @ dgiW + rsum*b)
    mgemm_k<1, 3, 0, 1><<<dim3(NT_O, MT), 256, 0, stream>>>(
        U_bf, dgiWt, dgi_b, rsum, dgi_prelu, zB_bf, nullptr, dflag, N, HID, OUT, OUT);
    mgemm_k<1, 3, 0, 1><<<dim3(NT_O, MT), 256, 0, stream>>>(
        Up_bf, dgiWt, dgi_b, rsum, dgi_prelu, h2_bf, nullptr, dflag, N, HID, OUT, OUT);

    colsum_k<<<(N + 127) / 128, 320, 0, stream>>>(zB_bf, c_acc, N, OUT, 128);
    cfinal_k<<<1, 320, 0, stream>>>(c_acc, c_vec, cnorm, N, OUT);
    cos_k<0><<<256, 256, 0, stream>>>(zB_bf, c_vec, cnorm, &lacc[1], N, OUT);
    cos_k<1><<<256, 256, 0, stream>>>(h2_bf, c_vec, cnorm, &lacc[2], N, OUT);

    final_k<<<1, 64, 0, stream>>>(lacc, d_out, dflag, S * OUT, N);
}